// Round 1
// 131.759 us; speedup vs baseline: 1.0254x; 1.0254x over previous
//
#include <hip/hip_runtime.h>
#include <math.h>

typedef _Float16 h4 __attribute__((ext_vector_type(4)));
typedef _Float16 h8 __attribute__((ext_vector_type(8)));
typedef __fp16   p2 __attribute__((ext_vector_type(2)));   // cvt_pkrtz result type
typedef float    f4 __attribute__((ext_vector_type(4)));

#define NPAIR (8*256*256)
#define NTILE (NPAIR/16)          // 32768 tiles of 16 pairs
#define BLOCKS 2048
#define ITERS (NTILE/(BLOCKS*4))  // 4 tiles per wave

// 16x16x16 f16 MFMA: C/D layout (row=4q+reg, col=lane&15).
// 16x16x32 f16 MFMA (gfx950): A/B frag k-contiguous: lane(q,nn) elem j -> k=8q+j.
#define MFMA16(a,b,c) __builtin_amdgcn_mfma_f32_16x16x16f16((a),(b),(c),0,0,0)
#define MFMA32(a,b,c) __builtin_amdgcn_mfma_f32_16x16x32_f16((a),(b),(c),0,0,0)
#define FENCE() asm volatile("" ::: "memory")

#define LOG2E 1.44269504088896340736f
#define LN2   0.69314718055994530942f

// Channel permutation: logical channel sitting at (tile t, row m) of every
// 64-wide layer output. Chosen so a K=32 B-frag (k=8q+j contiguous) is exactly
// concat(pk4(C/D tile 2c), pk4(C/D tile 2c+1)) on the same lane, AND the
// position->channel map is the identity (position kappa(t,m) == chperm(t,m)),
// so the NEXT layer's weight k-axis needs no permutation.
__device__ __forceinline__ int chperm(int t, int m)
{
    return 32*(t>>1) + 8*(m>>2) + 4*(t&1) + (m&3);
}

// A-fragment pool:
// [0,256)     h4: W1^T K=16 frags: t*64+lane; out-ch = chperm(t,nn);
//             k=4q+j: k<9 -> W1[k][ch]*log2e; k==9 -> b1[ch]*log2e; else 0.
//             (log2e folded: L1 output H' = h*log2e, silu uses exp2 directly)
// [256,2304)  W2'^T as h4-PAIRS forming h8 K=32 frags:
//             g2=(enc*4+ct)*2+c; idx=256+g2*128+lane*2+h; elem j:
//             k=32c+8q+4h+j (orig hidden ch, identity k-axis),
//             val=W2[k][ech]*fg[enc][ech]*ln2, ech=chperm(ct,nn).
// [2304,4352) Wg1^T same packing: g3=vt*4+c; idx=2304+g3*128+lane*2+h;
//             k=32c+8q+4h+j (gate-in ch 0..127), val=Wg1[k][gch]*log2e,
//             gch=chperm(vt,nn).
__device__ h4 g_all[4352];
// Per-channel epilogue constants, PERMUTED to position order (16t+m -> chperm(t,m)):
// [0,128) b2*fg+fb per enc  [128,192) bg1*log2e
// [192,256) (Wg2[c][1]-Wg2[c][0])*ln2  [256,320) ln_g*Wo
__device__ float g_cst[320];
__device__ float g_cc[2];         // C0 = sum ln_b*Wo, C1 = sum ln_g*Wo

__global__ void prep_kernel(const float* __restrict__ W1, const float* __restrict__ b1,
                            const float* __restrict__ W2, const float* __restrict__ b2,
                            const float* __restrict__ fgam, const float* __restrict__ fbet,
                            const float* __restrict__ Wg1, const float* __restrict__ bg1,
                            const float* __restrict__ Wg2,
                            const float* __restrict__ ln_g, const float* __restrict__ ln_b,
                            const float* __restrict__ Wo)
{
    int idx = blockIdx.x * 256 + threadIdx.x;
    if (idx < 256) {
        int lane = idx & 63, q = lane >> 4, nn = lane & 15;
        int t = idx >> 6;
        int ch = chperm(t, nn);
        h4 v;
#pragma unroll
        for (int j = 0; j < 4; ++j) {
            int k = 4*q + j;
            float x = (k < 9) ? W1[k*64 + ch] : (k == 9 ? b1[ch] : 0.f);
            v[j] = (_Float16)(x * LOG2E);
        }
        g_all[idx] = v;
    } else if (idx < 2304) {
        int z = idx - 256;
        int g2 = z >> 7, rem = z & 127, lane = rem >> 1, h = rem & 1;
        int q = lane >> 4, nn = lane & 15;
        int c = g2 & 1, ct = (g2 >> 1) & 3, enc = g2 >> 3;
        int ech = chperm(ct, nn);
        float fgv = fgam[enc*64 + ech] * LN2;
        h4 v;
#pragma unroll
        for (int j = 0; j < 4; ++j) {
            int k = 32*c + 8*q + 4*h + j;
            v[j] = (_Float16)(W2[k*64 + ech] * fgv);
        }
        g_all[idx] = v;
    } else if (idx < 4352) {
        int z = idx - 2304;
        int g3 = z >> 7, rem = z & 127, lane = rem >> 1, h = rem & 1;
        int q = lane >> 4, nn = lane & 15;
        int c = g3 & 3, vt = g3 >> 2;
        int gch = chperm(vt, nn);
        h4 v;
#pragma unroll
        for (int j = 0; j < 4; ++j) {
            int k = 32*c + 8*q + 4*h + j;
            v[j] = (_Float16)(Wg1[k*64 + gch] * LOG2E);
        }
        g_all[idx] = v;
    } else if (idx >= 4352 && idx < 4416) {
        // wave-parallel reduction (was a 64-iter serial loop on one thread)
        int k = idx - 4352;
        float c0 = ln_b[k]*Wo[k], c1 = ln_g[k]*Wo[k];
#pragma unroll
        for (int s = 1; s < 64; s <<= 1) {
            c0 += __shfl_xor(c0, s);
            c1 += __shfl_xor(c1, s);
        }
        if (k == 0) { g_cc[0] = c0; g_cc[1] = c1; }
    } else if (idx >= 4608 && idx < 4928) {
        int c = idx - 4608;
        float v;
        if (c < 128) {
            int enc = c >> 6, p = c & 63, t = p >> 4, m = p & 15;
            int ch = chperm(t, m);
            v = fmaf(b2[ch], fgam[enc*64 + ch], fbet[enc*64 + ch]);
        } else if (c < 192) {
            int p = c - 128, t = p >> 4, m = p & 15;
            v = bg1[chperm(t, m)] * LOG2E;
        } else if (c < 256) {
            int p = c - 192, t = p >> 4, m = p & 15;
            int ch = chperm(t, m);
            v = (Wg2[2*ch+1] - Wg2[2*ch]) * LN2;
        } else {
            int p = c - 256, t = p >> 4, m = p & 15;
            int ch = chperm(t, m);
            v = ln_g[ch] * Wo[ch];
        }
        g_cst[c] = v;
    }
}

__device__ __forceinline__ float sig(float x) { return __builtin_amdgcn_rcpf(1.f + __expf(-x)); }

// x' = x*log2e already (folded into weights): returns x'*sigmoid(x) = log2e*silu(x)
// (the trailing ln2 is folded into the consumer's weights/consts).
// Per element: v_exp_f32(-x') [neg modifier, free] + v_add + v_rcp + v_mul.
__device__ __forceinline__ float xsig(float x)
{
    return x * __builtin_amdgcn_rcpf(1.f + __builtin_amdgcn_exp2f(-x));
}

__device__ __forceinline__ f4 xsig4(f4 v)
{
    f4 r; r[0] = xsig(v[0]); r[1] = xsig(v[1]); r[2] = xsig(v[2]); r[3] = xsig(v[3]);
    return r;
}

__device__ __forceinline__ h8 pk8(f4 a, f4 b)   // two f32x4 -> one h8 (K=32 B-frag half-pair)
{
    p2 x0 = __builtin_amdgcn_cvt_pkrtz(a[0], a[1]);
    p2 x1 = __builtin_amdgcn_cvt_pkrtz(a[2], a[3]);
    p2 x2 = __builtin_amdgcn_cvt_pkrtz(b[0], b[1]);
    p2 x3 = __builtin_amdgcn_cvt_pkrtz(b[2], b[3]);
    h8 r;
    r[0]=(_Float16)x0[0]; r[1]=(_Float16)x0[1]; r[2]=(_Float16)x1[0]; r[3]=(_Float16)x1[1];
    r[4]=(_Float16)x2[0]; r[5]=(_Float16)x2[1]; r[6]=(_Float16)x3[0]; r[7]=(_Float16)x3[1];
    return r;
}

// R17 = R16 with: (a) L2/gate1 on 16x16x32 f16 MFMA (64->32 MFMAs, 64 ds_read_b64
// -> 32 ds_read_b128 A-frag fetches) via the chperm channel-permutation so B-frags
// chain in-register with zero shuffles; (b) exp2-domain silu (log2e/ln2 folded into
// prep) removing one v_mul per silu element (48/tile); (c) wave-parallel prep reduce.
__global__ __launch_bounds__(256, 4) void fused_kernel(
    const float* __restrict__ coords, const float* __restrict__ cost,
    const float* __restrict__ lscale, const float* __restrict__ bg2,
    const float* __restrict__ gt, const float* __restrict__ bo,
    float* __restrict__ out)
{
    __shared__ __align__(16) char smem[32768 + 1280 + 4*1280];
    const int tid = threadIdx.x;
    const int wave = tid >> 6, lane = tid & 63;
    const int q = lane >> 4, nn = lane & 15;
    const int q4 = q*4;

    h4* wpool = (h4*)smem;                    // [0,2048) W2' h4s, [2048,4096) Wg1 h4s
    for (int z = tid; z < 4096; z += 256) wpool[z] = g_all[256 + z];
    float* cpool = (float*)(smem + 32768);    // 320 epilogue consts
    for (int z = tid; z < 320; z += 256) cpool[z] = g_cst[z];
    __syncthreads();

    _Float16* U = (_Float16*)(smem + 34048 + wave*1280);  // feat: [enc][16 pairs][20]
    for (int z = lane; z < 320; z += 64) ((float*)U)[z] = 0.f;  // zero pads once

    // W1^T A-frags, register-resident (8 VGPRs)
    h4 w1a0 = g_all[lane], w1a1 = g_all[64+lane], w1a2 = g_all[128+lane], w1a3 = g_all[192+lane];

    const float dlgb = bg2[1] - bg2[0];
    const float s0 = __expf(lscale[0]), s1 = __expf(lscale[1]);
    const float invT = __expf(-gt[0]);
    const float outc = g_cc[0] + bo[0], C1 = g_cc[1];

    const int wgid = blockIdx.x*4 + wave;

    for (int it = 0; it < ITERS; ++it) {
        const int T = wgid + it*(BLOCKS*4);
        const int p0 = T*16;
        const int bb = p0 >> 16, ii = (p0 >> 8) & 255, j0 = p0 & 255;
        // ---- features: lanes 0-15 cost enc, 16-31 angle enc; 1 LDS hop ----
        const float xc = cost[p0 + nn];
        const float* cb = coords + (bb << 9);
        const float xi = cb[2*ii], yi = cb[2*ii+1];
        const float xj = cb[2*(j0+nn)], yj = cb[2*(j0+nn)+1];
        const float ang = atan2f(yi - yj, xi - xj);
        const int isA = q & 1;
        const float xv = isA ? ang : xc;
        const float sE = isA ? s1 : s0;
        FENCE();
        if (lane < 32) {
            const float sn1 = __sinf(xv), cs1 = __cosf(xv);
            const float sn2 = 2.f*sn1*cs1, cs2 = fmaf(-2.f*sn1, sn1, 1.f);
            const float sn4 = 2.f*sn2*cs2, cs4 = fmaf(-2.f*sn2, sn2, 1.f);
            const float sn8 = 2.f*sn4*cs4, cs8 = fmaf(-2.f*sn4, sn4, 1.f);
            _Float16* fp = U + isA*320 + nn*20;
            p2 p01 = __builtin_amdgcn_cvt_pkrtz(xv*sE,  sn1*sE);
            p2 p23 = __builtin_amdgcn_cvt_pkrtz(cs1*sE, sn2*sE);
            p2 p45 = __builtin_amdgcn_cvt_pkrtz(cs2*sE, sn4*sE);
            p2 p67 = __builtin_amdgcn_cvt_pkrtz(cs4*sE, sn8*sE);
            p2 p89 = __builtin_amdgcn_cvt_pkrtz(cs8*sE, 1.0f);  // k=9: homogeneous 1 (W1 row 9 = b1)
            h4 w0; w0[0]=(_Float16)p01[0]; w0[1]=(_Float16)p01[1];
                   w0[2]=(_Float16)p23[0]; w0[3]=(_Float16)p23[1];
            h4 w1_; w1_[0]=(_Float16)p45[0]; w1_[1]=(_Float16)p45[1];
                    w1_[2]=(_Float16)p67[0]; w1_[3]=(_Float16)p67[1];
            *(h4*)(fp)     = w0;   // ds_write_b64
            *(h4*)(fp + 4) = w1_;
            fp[8] = (_Float16)p89[0];   // cs8 term
            fp[9] = (_Float16)p89[1];   // homogeneous 1 -> W1 row 9 (= b1)
        }
        FENCE();
        // ---- L1: H'^T = (W1*log2e)^T @ feat^T (K=16 covers 9 feats + bias-1) ----
        h4 fB0 = *(h4*)(U + nn*20 + q4);
        h4 fB1 = *(h4*)(U + 320 + nn*20 + q4);
        const f4 z4 = {0.f, 0.f, 0.f, 0.f};
        f4 H00 = MFMA16(w1a0, fB0, z4), H01 = MFMA16(w1a1, fB0, z4);
        f4 H02 = MFMA16(w1a2, fB0, z4), H03 = MFMA16(w1a3, fB0, z4);
        f4 H10 = MFMA16(w1a0, fB1, z4), H11 = MFMA16(w1a1, fB1, z4);
        f4 H12 = MFMA16(w1a2, fB1, z4), H13 = MFMA16(w1a3, fB1, z4);
        // exp2-silu -> f16 K=32 B-frags (chperm makes concat of tile pairs = k-contiguous frag)
        h8 hc0 = pk8(xsig4(H00), xsig4(H01));   // enc0, k 0..31
        h8 hc1 = pk8(xsig4(H02), xsig4(H03));   // enc0, k 32..63
        h8 hc2 = pk8(xsig4(H10), xsig4(H11));   // enc1, k 0..31
        h8 hc3 = pk8(xsig4(H12), xsig4(H13));   // enc1, k 32..63
        // launder pool index: block LICM from hoisting weight frags / consts to regs
        int wofs = 0; asm volatile("" : "+s"(wofs));
        const h8* wp = (const h8*)wpool + wofs;       // W2' frags [0,1024), Wg1 [1024,2048)
        const float* cstl = cpool + wofs;
        // ---- L2: e^T = (W2'*ln2)^T @ H'^T + b2' (FiLM folded; K=64 = 2 chunks) ----
        f4 E00 = *(f4*)(cstl + q4);
        f4 E01 = *(f4*)(cstl + 16 + q4);
        f4 E02 = *(f4*)(cstl + 32 + q4);
        f4 E03 = *(f4*)(cstl + 48 + q4);
        f4 E10 = *(f4*)(cstl + 64 + q4);
        f4 E11 = *(f4*)(cstl + 80 + q4);
        f4 E12 = *(f4*)(cstl + 96 + q4);
        f4 E13 = *(f4*)(cstl + 112 + q4);
        E00=MFMA32(wp[ 0*64+lane],hc0,E00); E00=MFMA32(wp[ 1*64+lane],hc1,E00);
        E01=MFMA32(wp[ 2*64+lane],hc0,E01); E01=MFMA32(wp[ 3*64+lane],hc1,E01);
        E02=MFMA32(wp[ 4*64+lane],hc0,E02); E02=MFMA32(wp[ 5*64+lane],hc1,E02);
        E03=MFMA32(wp[ 6*64+lane],hc0,E03); E03=MFMA32(wp[ 7*64+lane],hc1,E03);
        E10=MFMA32(wp[ 8*64+lane],hc2,E10); E10=MFMA32(wp[ 9*64+lane],hc3,E10);
        E11=MFMA32(wp[10*64+lane],hc2,E11); E11=MFMA32(wp[11*64+lane],hc3,E11);
        E12=MFMA32(wp[12*64+lane],hc2,E12); E12=MFMA32(wp[13*64+lane],hc3,E12);
        E13=MFMA32(wp[14*64+lane],hc2,E13); E13=MFMA32(wp[15*64+lane],hc3,E13);
        // e -> f16 K=32 B-frags for gate1; f32 E kept for fuse/LN
        h8 ec0 = pk8(E00, E01), ec1 = pk8(E02, E03);
        h8 ec2 = pk8(E10, E11), ec3 = pk8(E12, E13);
        // ---- gate1: G' = (Wg1*log2e)^T @ [e0|e1]^T + bg1' (K=128 = 4 chunks) ----
        f4 G0 = *(f4*)(cstl + 128 + q4);
        G0=MFMA32(wp[1024+ 0*64+lane],ec0,G0); G0=MFMA32(wp[1024+ 1*64+lane],ec1,G0);
        G0=MFMA32(wp[1024+ 2*64+lane],ec2,G0); G0=MFMA32(wp[1024+ 3*64+lane],ec3,G0);
        f4 G1 = *(f4*)(cstl + 144 + q4);
        G1=MFMA32(wp[1024+ 4*64+lane],ec0,G1); G1=MFMA32(wp[1024+ 5*64+lane],ec1,G1);
        G1=MFMA32(wp[1024+ 6*64+lane],ec2,G1); G1=MFMA32(wp[1024+ 7*64+lane],ec3,G1);
        f4 G2 = *(f4*)(cstl + 160 + q4);
        G2=MFMA32(wp[1024+ 8*64+lane],ec0,G2); G2=MFMA32(wp[1024+ 9*64+lane],ec1,G2);
        G2=MFMA32(wp[1024+10*64+lane],ec2,G2); G2=MFMA32(wp[1024+11*64+lane],ec3,G2);
        f4 G3 = *(f4*)(cstl + 176 + q4);
        G3=MFMA32(wp[1024+12*64+lane],ec0,G3); G3=MFMA32(wp[1024+13*64+lane],ec1,G3);
        G3=MFMA32(wp[1024+14*64+lane],ec2,G3); G3=MFMA32(wp[1024+15*64+lane],ec3,G3);
        G0 = xsig4(G0); G1 = xsig4(G1); G2 = xsig4(G2); G3 = xsig4(G3);
        // ---- gate2 (VALU): logit diff = sum_v silu(g)[v]*wd[v] (ln2 folded in wd) ----
        f4 wd0 = *(f4*)(cstl + 192 + q4), wd1 = *(f4*)(cstl + 208 + q4);
        f4 wd2 = *(f4*)(cstl + 224 + q4), wd3 = *(f4*)(cstl + 240 + q4);
        f4 pv = G0*wd0 + G1*wd1 + G2*wd2 + G3*wd3;
        float part = (pv[0]+pv[1]) + (pv[2]+pv[3]);
        part += __shfl_xor(part, 16); part += __shfl_xor(part, 32);
        const float w1 = sig((part + dlgb)*invT);
        // ---- fuse + LayerNorm + head (f32, per-lane partials + 2 shfl each) ----
        f4 gw0 = *(f4*)(cstl + 256 + q4), gw1 = *(f4*)(cstl + 272 + q4);
        f4 gw2 = *(f4*)(cstl + 288 + q4), gw3 = *(f4*)(cstl + 304 + q4);
        f4 fu0 = E00 + w1*(E10-E00);
        f4 fu1 = E01 + w1*(E11-E01);
        f4 fu2 = E02 + w1*(E12-E02);
        f4 fu3 = E03 + w1*(E13-E03);
        f4 sfv = (fu0+fu1)+(fu2+fu3);
        float sv = (sfv[0]+sfv[1])+(sfv[2]+sfv[3]);
        f4 sfq = (fu0*fu0+fu1*fu1)+(fu2*fu2+fu3*fu3);
        float sq = (sfq[0]+sfq[1])+(sfq[2]+sfq[3]);
        f4 sfd = (fu0*gw0+fu1*gw1)+(fu2*gw2+fu3*gw3);
        float dt = (sfd[0]+sfd[1])+(sfd[2]+sfd[3]);
        sv += __shfl_xor(sv, 16); sv += __shfl_xor(sv, 32);
        sq += __shfl_xor(sq, 16); sq += __shfl_xor(sq, 32);
        dt += __shfl_xor(dt, 16); dt += __shfl_xor(dt, 32);
        const float mu = sv * (1.f/64.f);
        const float vv = sq * (1.f/64.f) - mu*mu;
        const float rs = __builtin_amdgcn_rsqf(vv + 1e-5f);
        const float o = fmaf(rs, dt - mu*C1, outc);
        if (lane < 16) out[p0 + lane] = o;
    }
}

extern "C" void kernel_launch(void* const* d_in, const int* in_sizes, int n_in,
                              void* d_out, int out_size, void* d_ws, size_t ws_size,
                              hipStream_t stream)
{
    const float* coords = (const float*)d_in[0];
    const float* cost   = (const float*)d_in[1];
    const float* lscale = (const float*)d_in[2];
    const float* W1     = (const float*)d_in[3];
    const float* b1     = (const float*)d_in[4];
    const float* W2     = (const float*)d_in[5];
    const float* b2     = (const float*)d_in[6];
    const float* fg     = (const float*)d_in[7];
    const float* fb     = (const float*)d_in[8];
    const float* Wg1    = (const float*)d_in[9];
    const float* bg1    = (const float*)d_in[10];
    const float* Wg2    = (const float*)d_in[11];
    const float* bg2    = (const float*)d_in[12];
    const float* gt     = (const float*)d_in[13];
    const float* lng    = (const float*)d_in[14];
    const float* lnb    = (const float*)d_in[15];
    const float* Wo     = (const float*)d_in[16];
    const float* bo     = (const float*)d_in[17];
    float* out = (float*)d_out;

    prep_kernel<<<20, 256, 0, stream>>>(W1, b1, W2, b2, fg, fb, Wg1, bg1, Wg2, lng, lnb, Wo);
    fused_kernel<<<BLOCKS, 256, 0, stream>>>(coords, cost, lscale, bg2, gt, bo, out);
}

// Round 2
// 124.911 us; speedup vs baseline: 1.0817x; 1.0548x over previous
//
#include <hip/hip_runtime.h>
#include <math.h>

typedef _Float16 h4  __attribute__((ext_vector_type(4)));
typedef _Float16 h8  __attribute__((ext_vector_type(8)));
typedef __fp16   p2  __attribute__((ext_vector_type(2)));   // cvt_pkrtz result type
typedef float    f4  __attribute__((ext_vector_type(4)));
typedef float    f16x __attribute__((ext_vector_type(16)));

#define NPAIR (8*256*256)
#define NTILE32 (NPAIR/32)        // 16384 tiles of 32 pairs
#define BLOCKS 2048
#define ITERS (NTILE32/(BLOCKS*4))  // 2 tiles per wave

// 32x32x16 f16 MFMA (gfx950): C/D: col=lane&31, row=(reg&3)+8*(reg>>2)+4*(lane>>5)
// A/B (extrapolated from verified 16x16x32 k-contiguity): m/n=lane&31, k=8*(lane>>5)+j
#define MFMA(a,b,c) __builtin_amdgcn_mfma_f32_32x32x16_f16((a),(b),(c),0,0,0)
#define FENCE() asm volatile("" ::: "memory")

#define LOG2E 1.44269504088896340736f
#define LN2   0.69314718055994530942f

// Physical->logical channel permutation for 64-wide layers built from two 32x32
// C/D tiles: physical P = 32*mt + (g&3)+8*(g>>2)+4*hi  holds logical channel
// kappa = 32*mt + 16*(g>>3) + 8*hi + (g&7).  With B-frag chunk c built as
// pk8(C[mt=c>>1] regs 8*(c&1)..+7), slot (c,hi,j) then holds logical 16c+8hi+j
// == the MFMA k-index -> layers chain in-register with identity k-axis.
__device__ __forceinline__ int pi64(int P)
{
    int mt = P >> 5, r = P & 31;
    int hi = (r >> 2) & 1;
    int g  = (r & 3) + 4*(r >> 3);
    return 32*mt + 16*(g >> 3) + 8*hi + (g & 7);
}

// A-fragment pool (h8 units):
// [0,128)      W1^T  frags [mt][lane]: elem j: k=8*(lane>>5)+j;
//              k<9 -> W1[k][pi(32mt+(lane&31))]*log2e; k==9 -> b1*log2e; else 0
// [128,1152)   W2'^T frags [(enc*2+mt)*4+c][lane]: k=16c+8*(lane>>5)+j;
//              val = W2[k][P]*fg[enc][P]*ln2, P=pi(32mt+(lane&31))
// [1152,2176)  Wg1^T frags [mt*8+cc][lane]: in=64*(cc>>2)+16*(cc&3)+8*(lane>>5)+j;
//              val = Wg1[in][P]*log2e
__device__ h8 g_frag[2176];
// Epilogue consts in C/D order: flat = base + mt*32 + hi*16 + g:
// [0,128) E-init (enc major)  [128,192) bg1*log2e  [192,256) (Wg2[1]-Wg2[0])*ln2
// [256,320) ln_g*Wo
__device__ float g_cst[320];
__device__ float g_cc[2];         // C0 = sum ln_b*Wo, C1 = sum ln_g*Wo

__global__ void prep_kernel(const float* __restrict__ W1, const float* __restrict__ b1,
                            const float* __restrict__ W2, const float* __restrict__ b2,
                            const float* __restrict__ fgam, const float* __restrict__ fbet,
                            const float* __restrict__ Wg1, const float* __restrict__ bg1,
                            const float* __restrict__ Wg2,
                            const float* __restrict__ ln_g, const float* __restrict__ ln_b,
                            const float* __restrict__ Wo)
{
    int idx = blockIdx.x * 256 + threadIdx.x;
    if (idx < 2176) {
        h8 v;
        if (idx < 128) {
            int mt = idx >> 6, L = idx & 63;
            int hi = L >> 5, m = L & 31;
            int P = pi64(32*mt + m);
#pragma unroll
            for (int j = 0; j < 8; ++j) {
                int k = 8*hi + j;
                float x = (k < 9) ? W1[k*64 + P] : (k == 9 ? b1[P] : 0.f);
                v[j] = (_Float16)(x * LOG2E);
            }
        } else if (idx < 1152) {
            int z = idx - 128; int f = z >> 6, L = z & 63;
            int c = f & 3, mt = (f >> 2) & 1, enc = f >> 3;
            int hi = L >> 5, m = L & 31;
            int P = pi64(32*mt + m);
            float fgv = fgam[enc*64 + P] * LN2;
#pragma unroll
            for (int j = 0; j < 8; ++j) {
                int k = 16*c + 8*hi + j;
                v[j] = (_Float16)(W2[k*64 + P] * fgv);
            }
        } else {
            int z = idx - 1152; int f = z >> 6, L = z & 63;
            int cc = f & 7, mt = f >> 3;
            int hi = L >> 5, m = L & 31;
            int P = pi64(32*mt + m);
#pragma unroll
            for (int j = 0; j < 8; ++j) {
                int in = 64*(cc >> 2) + 16*(cc & 3) + 8*hi + j;
                v[j] = (_Float16)(Wg1[in*64 + P] * LOG2E);
            }
        }
        g_frag[idx] = v;
    } else if (idx >= 4352 && idx < 4416) {
        int k = idx - 4352;
        float c0 = ln_b[k]*Wo[k], c1 = ln_g[k]*Wo[k];
#pragma unroll
        for (int s = 1; s < 64; s <<= 1) {
            c0 += __shfl_xor(c0, s);
            c1 += __shfl_xor(c1, s);
        }
        if (k == 0) { g_cc[0] = c0; g_cc[1] = c1; }
    } else if (idx >= 4608 && idx < 4928) {
        int c = idx - 4608;
        float v;
        if (c < 128) {
            int enc = c >> 6, w = c & 63;
            int mt = w >> 5, hi = (w >> 4) & 1, g = w & 15;
            int P = pi64(32*mt + (g & 3) + 8*(g >> 2) + 4*hi);
            v = fmaf(b2[P], fgam[enc*64 + P], fbet[enc*64 + P]);
        } else if (c < 192) {
            int w = c - 128, mt = w >> 5, hi = (w >> 4) & 1, g = w & 15;
            int P = pi64(32*mt + (g & 3) + 8*(g >> 2) + 4*hi);
            v = bg1[P] * LOG2E;
        } else if (c < 256) {
            int w = c - 192, mt = w >> 5, hi = (w >> 4) & 1, g = w & 15;
            int P = pi64(32*mt + (g & 3) + 8*(g >> 2) + 4*hi);
            v = (Wg2[2*P+1] - Wg2[2*P]) * LN2;
        } else {
            int w = c - 256, mt = w >> 5, hi = (w >> 4) & 1, g = w & 15;
            int P = pi64(32*mt + (g & 3) + 8*(g >> 2) + 4*hi);
            v = ln_g[P] * Wo[P];
        }
        g_cst[c] = v;
    }
}

// x' = x*log2e (folded into weights): x'*sigmoid(x) = log2e*silu(x); trailing ln2
// folded into the consumer. 2 trans + 2 VALU per element.
__device__ __forceinline__ f16x xsig16(f16x v)
{
#pragma unroll
    for (int i = 0; i < 16; ++i)
        v[i] = v[i] * __builtin_amdgcn_rcpf(1.f + __builtin_amdgcn_exp2f(-v[i]));
    return v;
}

template<int B>
__device__ __forceinline__ h8 pk8(const f16x& v)   // C/D regs B..B+7 -> h8 B-frag
{
    p2 a = __builtin_amdgcn_cvt_pkrtz(v[B+0], v[B+1]);
    p2 b = __builtin_amdgcn_cvt_pkrtz(v[B+2], v[B+3]);
    p2 c = __builtin_amdgcn_cvt_pkrtz(v[B+4], v[B+5]);
    p2 d = __builtin_amdgcn_cvt_pkrtz(v[B+6], v[B+7]);
    h8 r;
    r[0]=a[0]; r[1]=a[1]; r[2]=b[0]; r[3]=b[1];
    r[4]=c[0]; r[5]=c[1]; r[6]=d[0]; r[7]=d[1];
    return r;
}

__device__ __forceinline__ h8 cat(h4 a, h4 b)
{
    h8 r;
#pragma unroll
    for (int i = 0; i < 4; ++i) { r[i] = a[i]; r[4+i] = b[i]; }
    return r;
}

__device__ __forceinline__ f16x ld16(const float* p)
{
    const f4* q = (const f4*)p;
    f4 a = q[0], b = q[1], c = q[2], d = q[3];
    f16x r;
#pragma unroll
    for (int i = 0; i < 4; ++i) { r[i] = a[i]; r[4+i] = b[i]; r[8+i] = c[i]; r[12+i] = d[i]; }
    return r;
}

__device__ __forceinline__ float hsum16(const f16x& v)
{
    float a0 = (v[0]+v[1])+(v[2]+v[3]);
    float a1 = (v[4]+v[5])+(v[6]+v[7]);
    float a2 = (v[8]+v[9])+(v[10]+v[11]);
    float a3 = (v[12]+v[13])+(v[14]+v[15]);
    return (a0+a1)+(a2+a3);
}

__device__ __forceinline__ float dot16(const f16x& a, const f16x& b)
{
    float d0 = a[0]*b[0], d1 = a[1]*b[1], d2 = a[2]*b[2], d3 = a[3]*b[3];
#pragma unroll
    for (int i = 4; i < 16; i += 4) {
        d0 = fmaf(a[i+0], b[i+0], d0);
        d1 = fmaf(a[i+1], b[i+1], d1);
        d2 = fmaf(a[i+2], b[i+2], d2);
        d3 = fmaf(a[i+3], b[i+3], d3);
    }
    return (d0+d1)+(d2+d3);
}

// R18 = R17 restructured to 32-pair tiles on 32x32x16 MFMAs:
// - feature phase uses ALL 64 lanes (lane&31=pair, lane>>5=enc): per-pair cost halves
// - fast poly atan2 (err ~1e-5 << f16 rounding); sin/cos of angle EXACT via dy/r, dx/r
// - 36 MFMAs/32 pairs vs 72 K16-equiv; A-frag ds_reads halve; epilogue 1 shfl per reduce
// LDS 44288 -> 3 blocks/CU; bounds(256,3) caps VGPR at 170 (est. peak ~146).
__global__ __launch_bounds__(256, 3) void fused_kernel(
    const float* __restrict__ coords, const float* __restrict__ cost,
    const float* __restrict__ lscale, const float* __restrict__ bg2,
    const float* __restrict__ gt, const float* __restrict__ bo,
    float* __restrict__ out)
{
    __shared__ __align__(16) char smem[32768 + 1280 + 4*2560];
    const int tid = threadIdx.x;
    const int wave = tid >> 6, lane = tid & 63;
    const int pr = lane & 31, hb = lane >> 5;

    h8* wpool = (h8*)smem;                    // [0,1024) W2' frags, [1024,2048) Wg1 frags
    for (int z = tid; z < 2048; z += 256) wpool[z] = g_frag[128 + z];
    float* cpool = (float*)(smem + 32768);    // 320 epilogue consts
    for (int z = tid; z < 320; z += 256) cpool[z] = g_cst[z];
    __syncthreads();

    float* Uf = (float*)(smem + 34048 + wave*2560);   // feat: [enc][32 pairs][20 f16]
    for (int z = lane; z < 640; z += 64) Uf[z] = 0.f; // zero pads once (k=10..15 stay 0)
    _Float16* Uh = (_Float16*)Uf;

    // W1^T A-frags, register-resident (8 VGPRs)
    h8 w1a0 = g_frag[lane], w1a1 = g_frag[64 + lane];

    const float dlgb = bg2[1] - bg2[0];
    const float sc0 = __expf(lscale[0]), sc1 = __expf(lscale[1]);
    const float invT2 = __expf(-gt[0]) * LOG2E;
    const float outc = g_cc[0] + bo[0], C1 = g_cc[1];

    const int wgid = blockIdx.x*4 + wave;

    for (int it = 0; it < ITERS; ++it) {
        const int T = wgid + it*(BLOCKS*4);
        const int p0 = T*32;
        const int bb = p0 >> 16, ii = (p0 >> 8) & 255, j0 = p0 & 255;
        // ---- features: all 64 lanes useful (enc = hb) ----
        const float xc = cost[p0 + pr];
        const float* cb = coords + (bb << 9);
        const float xi = cb[2*ii], yi = cb[2*ii+1];
        const float xj = cb[2*(j0+pr)], yj = cb[2*(j0+pr)+1];
        const float dx = xi - xj, dy = yi - yj;
        const float r2 = dx*dx + dy*dy;
        const float rinv = __builtin_amdgcn_rsqf(r2);
        // fast atan2(dy,dx): minimax deg-11, |err|~1e-5 (f16 feature ulp ~1e-3)
        const float ax = fabsf(dx), ay = fabsf(dy);
        const float mx = fmaxf(ax, ay), mn = fminf(ax, ay);
        const float t = mn * __builtin_amdgcn_rcpf(mx);
        const float t2 = t*t;
        float pa = fmaf(t2, -0.0117212f, 0.05265332f);
        pa = fmaf(t2, pa, -0.11643287f);
        pa = fmaf(t2, pa, 0.19354346f);
        pa = fmaf(t2, pa, -0.33262347f);
        pa = fmaf(t2, pa, 0.99997726f);
        float a = t * pa;
        a = (ay > ax) ? 1.57079632679f - a : a;
        a = (dx < 0.f) ? 3.14159265359f - a : a;
        a = __int_as_float(__float_as_int(a) | (__float_as_int(dy) & 0x80000000));
        const bool ok = r2 > 0.f;                  // diagonal (i==j): angle=0
        const float ang = ok ? a : 0.f;
        const float s1a = ok ? dy*rinv : 0.f;      // sin(atan2) exact
        const float c1a = ok ? dx*rinv : 1.f;      // cos(atan2) exact
        const float sn1 = hb ? s1a : __sinf(xc);
        const float cs1 = hb ? c1a : __cosf(xc);
        const float xv  = hb ? ang : xc;
        const float sE  = hb ? sc1 : sc0;
        const float sn2 = 2.f*sn1*cs1, cs2 = fmaf(-2.f*sn1, sn1, 1.f);
        const float sn4 = 2.f*sn2*cs2, cs4 = fmaf(-2.f*sn2, sn2, 1.f);
        const float sn8 = 2.f*sn4*cs4, cs8 = fmaf(-2.f*sn4, sn4, 1.f);
        FENCE();
        {
            _Float16* fp = Uh + hb*640 + pr*20;
            p2 p01 = __builtin_amdgcn_cvt_pkrtz(xv*sE,  sn1*sE);
            p2 p23 = __builtin_amdgcn_cvt_pkrtz(cs1*sE, sn2*sE);
            p2 p45 = __builtin_amdgcn_cvt_pkrtz(cs2*sE, sn4*sE);
            p2 p67 = __builtin_amdgcn_cvt_pkrtz(cs4*sE, sn8*sE);
            p2 p89 = __builtin_amdgcn_cvt_pkrtz(cs8*sE, 1.0f);  // k=9: bias-1 (W1 row 9 = b1)
            h4 w0; w0[0]=(_Float16)p01[0]; w0[1]=(_Float16)p01[1];
                   w0[2]=(_Float16)p23[0]; w0[3]=(_Float16)p23[1];
            h4 w1_; w1_[0]=(_Float16)p45[0]; w1_[1]=(_Float16)p45[1];
                    w1_[2]=(_Float16)p67[0]; w1_[3]=(_Float16)p67[1];
            *(h4*)(fp)     = w0;     // ds_write_b64
            *(h4*)(fp + 4) = w1_;
            *(p2*)(fp + 8) = p89;    // ds_write_b32
        }
        FENCE();
        // ---- L1: H' = (W1*log2e)^T @ feat^T, K=16 (10 feats + zero pad) ----
        const _Float16* ub = Uh + pr*20 + 8*hb;
        h8 fb0 = cat(*(h4*)(ub),       *(h4*)(ub + 4));
        h8 fb1 = cat(*(h4*)(ub + 640), *(h4*)(ub + 644));
        const f16x z16 = {0.f,0.f,0.f,0.f,0.f,0.f,0.f,0.f,0.f,0.f,0.f,0.f,0.f,0.f,0.f,0.f};
        f16x H00 = MFMA(w1a0, fb0, z16);
        f16x H01 = MFMA(w1a1, fb0, z16);
        f16x H10 = MFMA(w1a0, fb1, z16);
        f16x H11 = MFMA(w1a1, fb1, z16);
        // launder pool pointers: block LICM from hoisting frags/consts into regs
        int wofs = 0; asm volatile("" : "+s"(wofs));
        const h8* wp = wpool + wofs;
        const float* cstl = cpool + wofs;
        // ---- L2 enc0 ----
        H00 = xsig16(H00); H01 = xsig16(H01);
        h8 hf0 = pk8<0>(H00), hf1 = pk8<8>(H00), hf2 = pk8<0>(H01), hf3 = pk8<8>(H01);
        f16x E00 = ld16(cstl + 16*hb);
        f16x E01 = ld16(cstl + 32 + 16*hb);
        E00 = MFMA(wp[0*64+lane], hf0, E00);
        E00 = MFMA(wp[1*64+lane], hf1, E00);
        E00 = MFMA(wp[2*64+lane], hf2, E00);
        E00 = MFMA(wp[3*64+lane], hf3, E00);
        E01 = MFMA(wp[4*64+lane], hf0, E01);
        E01 = MFMA(wp[5*64+lane], hf1, E01);
        E01 = MFMA(wp[6*64+lane], hf2, E01);
        E01 = MFMA(wp[7*64+lane], hf3, E01);
        // ---- L2 enc1 ----
        H10 = xsig16(H10); H11 = xsig16(H11);
        hf0 = pk8<0>(H10); hf1 = pk8<8>(H10); hf2 = pk8<0>(H11); hf3 = pk8<8>(H11);
        f16x E10 = ld16(cstl + 64 + 16*hb);
        f16x E11 = ld16(cstl + 96 + 16*hb);
        E10 = MFMA(wp[ 8*64+lane], hf0, E10);
        E10 = MFMA(wp[ 9*64+lane], hf1, E10);
        E10 = MFMA(wp[10*64+lane], hf2, E10);
        E10 = MFMA(wp[11*64+lane], hf3, E10);
        E11 = MFMA(wp[12*64+lane], hf0, E11);
        E11 = MFMA(wp[13*64+lane], hf1, E11);
        E11 = MFMA(wp[14*64+lane], hf2, E11);
        E11 = MFMA(wp[15*64+lane], hf3, E11);
        // ---- gate1: K=128 = enc0 chunks 0..3 then enc1 chunks 4..7 ----
        h8 ef0 = pk8<0>(E00), ef1 = pk8<8>(E00), ef2 = pk8<0>(E01), ef3 = pk8<8>(E01);
        f16x G0 = ld16(cstl + 128 + 16*hb);
        f16x G1 = ld16(cstl + 160 + 16*hb);
        G0 = MFMA(wp[1024+ 0*64+lane], ef0, G0);
        G0 = MFMA(wp[1024+ 1*64+lane], ef1, G0);
        G0 = MFMA(wp[1024+ 2*64+lane], ef2, G0);
        G0 = MFMA(wp[1024+ 3*64+lane], ef3, G0);
        G1 = MFMA(wp[1024+ 8*64+lane], ef0, G1);
        G1 = MFMA(wp[1024+ 9*64+lane], ef1, G1);
        G1 = MFMA(wp[1024+10*64+lane], ef2, G1);
        G1 = MFMA(wp[1024+11*64+lane], ef3, G1);
        ef0 = pk8<0>(E10); ef1 = pk8<8>(E10); ef2 = pk8<0>(E11); ef3 = pk8<8>(E11);
        G0 = MFMA(wp[1024+ 4*64+lane], ef0, G0);
        G0 = MFMA(wp[1024+ 5*64+lane], ef1, G0);
        G0 = MFMA(wp[1024+ 6*64+lane], ef2, G0);
        G0 = MFMA(wp[1024+ 7*64+lane], ef3, G0);
        G1 = MFMA(wp[1024+12*64+lane], ef0, G1);
        G1 = MFMA(wp[1024+13*64+lane], ef1, G1);
        G1 = MFMA(wp[1024+14*64+lane], ef2, G1);
        G1 = MFMA(wp[1024+15*64+lane], ef3, G1);
        G0 = xsig16(G0); G1 = xsig16(G1);
        // ---- gate2 (VALU): logit diff; in-lane 32 + 1 shfl (hi-half) ----
        f16x wd0 = ld16(cstl + 192 + 16*hb);
        f16x wd1 = ld16(cstl + 224 + 16*hb);
        float part = dot16(G0, wd0) + dot16(G1, wd1);
        part += __shfl_xor(part, 32);
        const float w1v = __builtin_amdgcn_rcpf(1.f + __builtin_amdgcn_exp2f(-(part + dlgb)*invT2));
        // ---- fuse + LayerNorm + head ----
        f16x gw0 = ld16(cstl + 256 + 16*hb);
        f16x gw1 = ld16(cstl + 288 + 16*hb);
        f16x fu0, fu1;
#pragma unroll
        for (int i = 0; i < 16; ++i) {
            fu0[i] = fmaf(w1v, E10[i]-E00[i], E00[i]);
            fu1[i] = fmaf(w1v, E11[i]-E01[i], E01[i]);
        }
        float sv = hsum16(fu0) + hsum16(fu1);
        float sq = dot16(fu0, fu0) + dot16(fu1, fu1);
        float dt = dot16(fu0, gw0) + dot16(fu1, gw1);
        sv += __shfl_xor(sv, 32);
        sq += __shfl_xor(sq, 32);
        dt += __shfl_xor(dt, 32);
        const float mu = sv * (1.f/64.f);
        const float vv = sq * (1.f/64.f) - mu*mu;
        const float rs = __builtin_amdgcn_rsqf(vv + 1e-5f);
        const float o = fmaf(rs, dt - mu*C1, outc);
        if (lane < 32) out[p0 + lane] = o;
    }
}

extern "C" void kernel_launch(void* const* d_in, const int* in_sizes, int n_in,
                              void* d_out, int out_size, void* d_ws, size_t ws_size,
                              hipStream_t stream)
{
    const float* coords = (const float*)d_in[0];
    const float* cost   = (const float*)d_in[1];
    const float* lscale = (const float*)d_in[2];
    const float* W1     = (const float*)d_in[3];
    const float* b1     = (const float*)d_in[4];
    const float* W2     = (const float*)d_in[5];
    const float* b2     = (const float*)d_in[6];
    const float* fg     = (const float*)d_in[7];
    const float* fb     = (const float*)d_in[8];
    const float* Wg1    = (const float*)d_in[9];
    const float* bg1    = (const float*)d_in[10];
    const float* Wg2    = (const float*)d_in[11];
    const float* bg2    = (const float*)d_in[12];
    const float* gt     = (const float*)d_in[13];
    const float* lng    = (const float*)d_in[14];
    const float* lnb    = (const float*)d_in[15];
    const float* Wo     = (const float*)d_in[16];
    const float* bo     = (const float*)d_in[17];
    float* out = (float*)d_out;

    prep_kernel<<<20, 256, 0, stream>>>(W1, b1, W2, b2, fg, fb, Wg1, bg1, Wg2, lng, lnb, Wo);
    fused_kernel<<<BLOCKS, 256, 0, stream>>>(coords, cost, lscale, bg2, gt, bo, out);
}